// Round 3
// baseline (352.879 us; speedup 1.0000x reference)
//
#include <hip/hip_runtime.h>

// TensorConvolutionTrainLayer: S=512,P=196,Q=48,CB=8,R=32,C=10,N=8
// R7: R5/R6 proved the kernel is NOT LDS-bound (8x Ash-traffic cut -> 0 time
// change; compiler had already AGPR-hoisted af in R5 — identical conflict
// counts). All pipes <35% busy => latency/ILP-bound at 2 waves/SIMD.
// This round: 8 waves per block (512 thr), same total work, same LDS (79 KB,
// 2 blocks/CU) -> 16 waves/CU = 4 waves/SIMD. Per-wave G tile M=32 (ab half
// h=w>>2) x N=32 (l=4cc+(w&3)); NS 2 m-tiles/wave. af hoist reverted (neutral).
//   sigma(a)=(a&1)*4+(a>>1); with a=h*4+mi*2+fqh: sigma=fqh*4+h*2+mi, so each
//   lane's 2 mi values are k'-adjacent -> b32 packed Gsh writes.
//   St3[c][l*8+sigma(a)] f16 doubles as state storage AND next B-operand.

typedef _Float16 half8 __attribute__((ext_vector_type(8)));
typedef _Float16 h2v   __attribute__((ext_vector_type(2)));
typedef float floatx4 __attribute__((ext_vector_type(4)));

#define KP 224    // P padded to 7*32
#define QP 64     // Q padded to 2*32
#define LDA2 232  // Mt2 row stride (halfs) = 29 x 16B chunks
#define GSTR 40   // Gsh row stride (halfs): 80B, 16B-aligned
#define SSTR 264  // St3 row stride (halfs): 528B, 16B-aligned

__device__ __forceinline__ void gld_lds16(const void* g, void* l) {
  __builtin_amdgcn_global_load_lds((const __attribute__((address_space(1))) void*)g,
                                   (__attribute__((address_space(3))) void*)l, 16, 0, 0);
}

// ---------------- generic MFMA GEMM (unchanged) ----------------
template<int K, int MODE>
__global__ __launch_bounds__(256)
void gemm_mfma(const _Float16* __restrict__ A, const _Float16* __restrict__ Bt,
               void* __restrict__ out0, void* __restrict__ out1, void* __restrict__ out2)
{
  __shared__ __align__(16) _Float16 Ash[128 * 32];
  __shared__ __align__(16) _Float16 Bsh[128 * 32];
  const int tid  = threadIdx.x;
  const int wave = tid >> 6;
  const int lane = tid & 63;
  const int m0 = blockIdx.y * 128;
  const int n0 = blockIdx.x * 128;
  const int wm = (wave >> 1) * 64;
  const int wn = (wave & 1) * 64;
  const int fr = lane & 15;
  const int fq = lane >> 4;

  floatx4 acc[4][4] = {};

  for (int kt = 0; kt < K; kt += 32) {
    __syncthreads();
#pragma unroll
    for (int j = 0; j < 2; j++) {
      const int c   = j * 256 + tid;
      const int row = c >> 2;
      const int ko  = (c & 3) * 8;
      gld_lds16(A  + (size_t)(m0 + row) * K + kt + ko,
                (char*)Ash + (size_t)(j * 256 + wave * 64) * 16);
      gld_lds16(Bt + (size_t)(n0 + row) * K + kt + ko,
                (char*)Bsh + (size_t)(j * 256 + wave * 64) * 16);
    }
    __syncthreads();
    half8 af[4], bf[4];
#pragma unroll
    for (int i = 0; i < 4; i++)
      af[i] = *(const half8*)&Ash[(wm + i * 16 + fr) * 32 + fq * 8];
#pragma unroll
    for (int i = 0; i < 4; i++)
      bf[i] = *(const half8*)&Bsh[(wn + i * 16 + fr) * 32 + fq * 8];
#pragma unroll
    for (int i = 0; i < 4; i++)
#pragma unroll
      for (int j = 0; j < 4; j++)
        acc[i][j] = __builtin_amdgcn_mfma_f32_16x16x32_f16(af[i], bf[j], acc[i][j], 0, 0, 0);
  }

#pragma unroll
  for (int i = 0; i < 4; i++) {
#pragma unroll
    for (int j = 0; j < 4; j++) {
#pragma unroll
      for (int r = 0; r < 4; r++) {
        const int m = m0 + wm + i * 16 + fq * 4 + r;
        const int n = n0 + wn + j * 16 + fr;
        const float v = acc[i][j][r];
        if constexpr (MODE == 0) {
          const unsigned s = (unsigned)n / 196u;
          const unsigned p = (unsigned)n - s * 196u;
          if (m < 8)
            ((_Float16*)out1)[((size_t)m * 512 + s) * KP + p] = (_Float16)v;
          else if (m < 392)
            ((_Float16*)out0)[((size_t)s * 384 + (m - 8)) * LDA2 + p] = (_Float16)v;
          else if (m < 400)
            ((_Float16*)out2)[((size_t)(m - 392) * 512 + s) * KP + p] = (_Float16)v;
        } else if constexpr (MODE == 2) {
          if (n < 320)
            ((float*)out0)[(size_t)(m & 511) * 2560 + (m >> 9) * 320 + n] = v;
        } else {
          if (n < 32)
            ((float*)out0)[(size_t)m * 32 + n] = v;
        }
      }
    }
  }
}

// ---------------- fused chain kernel (8 waves) ----------------
__device__ __forceinline__ void stageA8(const _Float16* __restrict__ base,
                                        _Float16* __restrict__ ash, int tid, int w) {
#pragma unroll
  for (int it = 0; it < 3; it++) {
    const int c = it * 512 + tid;
    gld_lds16(base + (size_t)c * 8, (char*)ash + (size_t)(it * 512 + w * 64) * 16);
  }
  if (tid < 320)
    gld_lds16(base + (size_t)(1536 + tid) * 8, (char*)ash + (size_t)(1536 + w * 64) * 16);
}

__global__ __launch_bounds__(512, 4)
void chain_kernel(const _Float16* __restrict__ Mt2, const _Float16* __restrict__ Akr,
                  const float* __restrict__ St0, const float* __restrict__ GN,
                  float* __restrict__ out)
{
  __shared__ __align__(16) _Float16 Ash[64 * LDA2];        // 29696 B
  __shared__ __align__(16) _Float16 Gsh[2][256 * GSTR];    // 40960 B
  __shared__ __align__(16) _Float16 St3[16 * SSTR];        // 8448 B
  __shared__ float oc[10];

  const int tid  = threadIdx.x;
  const int w    = tid >> 6;
  const int lane = tid & 63;
  const int s    = blockIdx.x;
  const int fr   = lane & 15;
  const int fq   = lane >> 4;
  const int fqh  = fq >> 1;
  const int fql  = fq & 1;
  const int h    = w >> 2;   // ab half: rows h*32..h*32+31
  const int wl   = w & 3;    // l within chunk: l = 4*cc + wl

  // init: St3[c][r*8+sigma(b)] from St0[s][b*320+r*10+c]; tid=(b,r) for tid<256
  if (tid < 256) {
    const int b = tid >> 5, r = tid & 31;
    const int kcol = r * 8 + ((b & 1) * 4 + (b >> 1));
    const float* src = St0 + (size_t)s * 2560 + (size_t)tid * 10;
#pragma unroll
    for (int c = 0; c < 10; c++) St3[c * SSTR + kcol] = (_Float16)src[c];
  }
  if (tid < 10) oc[tid] = 0.f;
  stageA8(Mt2 + (size_t)s * 384 * LDA2, Ash, tid, w);

  const int boff0 = fr * KP + fq * 8;   // B row offset for ni=0
  const int boff1 = boff0 + 16 * KP;    // ni=1

  // preload rolling B for (k=0, cc=0, kt=0,1)
  half8 bq[2][2];
  {
    const _Float16* Bb = Akr + (size_t)(wl * 32) * KP;
#pragma unroll
    for (int t2 = 0; t2 < 2; t2++) {
      bq[t2][0] = *(const half8*)(Bb + boff0 + t2 * 32);
      bq[t2][1] = *(const half8*)(Bb + boff1 + t2 * 32);
    }
  }
  __syncthreads();   // Ash + St3 ready (compiler drains vmcnt before barrier)

  const int ab0 = h * 32;

  for (int k = 0; k < 6; k++) {
    floatx4 ns[2] = {};   // NS accumulators: 2 m-tiles per wave

#pragma unroll 1
    for (int cc = 0; cc < 8; cc++) {
      const _Float16* Bc = Akr + ((size_t)k * 1024 + cc * 128 + wl * 32) * KP;
      // ---- G-phase: this wave's 32x32 slice (rows ab0.., cols l=4cc+wl) ----
      floatx4 acc[2][2] = {};
#pragma unroll
      for (int kt = 0; kt < 7; kt++) {
        half8 af[2];
#pragma unroll
        for (int mi = 0; mi < 2; mi++)
          af[mi] = *(const half8*)&Ash[(ab0 + mi * 16 + fr) * LDA2 + kt * 32 + fq * 8];
#pragma unroll
        for (int mi = 0; mi < 2; mi++) {
          acc[mi][0] = __builtin_amdgcn_mfma_f32_16x16x32_f16(af[mi], bq[kt & 1][0], acc[mi][0], 0, 0, 0);
          acc[mi][1] = __builtin_amdgcn_mfma_f32_16x16x32_f16(af[mi], bq[kt & 1][1], acc[mi][1], 0, 0, 0);
        }
        if (kt < 5) {   // rolling prefetch, distance 2 kt
          bq[kt & 1][0] = *(const half8*)(Bc + boff0 + (kt + 2) * 32);
          bq[kt & 1][1] = *(const half8*)(Bc + boff1 + (kt + 2) * 32);
        }
      }
      // pack 2 mi-values (k'-adjacent: k' = wl*8 + fqh*4 + h*2 + mi) + write
      {
        _Float16* gb = &Gsh[cc & 1][0];
        const int kcol = wl * 8 + fqh * 4 + h * 2;
#pragma unroll
        for (int ni = 0; ni < 2; ni++)
#pragma unroll
          for (int rg = 0; rg < 4; rg++) {
            h2v g2;
            g2[0] = (_Float16)acc[0][ni][rg];
            g2[1] = (_Float16)acc[1][ni][rg];
            const int m = (fql * 4 + rg) * 32 + ni * 16 + fr;
            *(h2v*)&gb[m * GSTR + kcol] = g2;
          }
      }
      __syncthreads();   // Gsh[cc&1] visible to all waves
      // refill bq for next chunk's kt=0,1 AFTER the barrier (so the vmcnt(0)
      // drain before s_barrier doesn't serialize on these loads)
      {
        int ncc = cc + 1, nk = k;
        if (ncc == 8) { ncc = 0; nk = k + 1; }
        if (nk < 6) {
          const _Float16* Bn = Akr + ((size_t)nk * 1024 + ncc * 128 + wl * 32) * KP;
#pragma unroll
          for (int t2 = 0; t2 < 2; t2++) {
            bq[t2][0] = *(const half8*)(Bn + boff0 + t2 * 32);
            bq[t2][1] = *(const half8*)(Bn + boff1 + t2 * 32);
          }
        }
      }
      if (cc == 7 && k < 5)   // all waves past G-phase reads: safe to restage Ash
        stageA8(Mt2 + ((size_t)s * 384 + 64 * (k + 1)) * LDA2, Ash, tid, w);
      // ---- NS-phase: NS[m][c] += G[m][k-slice] * St3[c][k-slice] ----
      {
        const _Float16* gb = &Gsh[cc & 1][0];
        const half8 bs = *(const half8*)&St3[fr * SSTR + cc * 32 + fq * 8];
#pragma unroll
        for (int t = 0; t < 2; t++) {
          const half8 aa = *(const half8*)&gb[(w * 32 + t * 16 + fr) * GSTR + fq * 8];
          ns[t] = __builtin_amdgcn_mfma_f32_16x16x32_f16(aa, bs, ns[t], 0, 0, 0);
        }
      }
    }

    __syncthreads();   // all NS reads of St3 done before overwrite; drains stageA
    // epilogue: NS -> St3 (next step's state / B operand). m=(b,r): k_next = r*8+sigma(b)
    if (fr < 10) {
#pragma unroll
      for (int t = 0; t < 2; t++) {
#pragma unroll
        for (int rg = 0; rg < 4; rg++) {
          const int m = w * 32 + t * 16 + fq * 4 + rg;
          const int b = m >> 5, r = m & 31;
          St3[fr * SSTR + r * 8 + ((b & 1) * 4 + (b >> 1))] = (_Float16)ns[t][rg];
        }
      }
    }
    // next iteration's cc=0 barrier orders these writes before any NS read
  }
  __syncthreads();

  // final: out[s,c] = sum_{a,l} St3[c][l*8+sigma(a)] * GN[a][s][l]
  if (tid < 256) {
    const int a = tid >> 5, l = tid & 31;
    const float gn = GN[((size_t)a * 512 + s) * 32 + l];
    const int kcol = l * 8 + ((a & 1) * 4 + (a >> 1));
#pragma unroll
    for (int c = 0; c < 10; c++) {
      float v = gn * (float)St3[c * SSTR + kcol];
#pragma unroll
      for (int o2 = 1; o2 < 64; o2 <<= 1) v += __shfl_xor(v, o2, 64);
      if (lane == 0) atomicAdd(&oc[c], v);
    }
  }
  __syncthreads();
  if (tid < 10) out[(size_t)s * 10 + tid] = oc[tid];
}

// ---------------- prep kernels (unchanged) ----------------
__global__ void prep_xh(const float* __restrict__ x, _Float16* __restrict__ xh) {
  const int idx = blockIdx.x * 256 + threadIdx.x;
  const int q = idx & 63, sp = idx >> 6;
  xh[idx] = (q < 48) ? (_Float16)x[sp * 48 + q] : (_Float16)0.f;
}

__global__ void prep_ckt(const float* __restrict__ cf, const float* __restrict__ cm,
                         const float* __restrict__ cl, _Float16* __restrict__ Ckt) {
  const int idx = blockIdx.x * 256 + threadIdx.x;
  const int q = idx & 63;
  const int row = idx >> 6;
  float v = 0.f;
  if (q < 48) {
    if (row < 8) v = cf[q * 8 + row];
    else if (row < 392) {
      const int rr = row - 8;
      const int k = rr >> 6, ab = rr & 63, a = ab >> 3, b = ab & 7;
      v = cm[((k * 8 + a) * 48 + q) * 8 + b];
    } else if (row < 400) v = cl[(row - 392) * 48 + q];
  }
  Ckt[idx] = (_Float16)v;
}

__global__ void prep_akr(const float* __restrict__ tm, _Float16* __restrict__ Akr) {
  const int idx = blockIdx.x * 256 + threadIdx.x;
  const int p = idx % 224;
  const int lr = (idx / 224) & 1023;
  const int k = idx / (224 * 1024);
  const int l = lr >> 5, r = lr & 31;
  float v = 0.f;
  if (p < 196) v = tm[(((k * 32 + l) * 196) + p) * 32 + r];
  Akr[idx] = (_Float16)v;
}

__global__ void prep_bt0(const float* __restrict__ tf, _Float16* __restrict__ Bt0) {
  const int idx = blockIdx.x * 256 + threadIdx.x;
  const int p = idx % 224;
  const int n = idx / 224;
  float v = 0.f;
  if (n < 320 && p < 196) {
    const int r = n / 10, c = n % 10;
    v = tf[(c * 196 + p) * 32 + r];
  }
  Bt0[idx] = (_Float16)v;
}

__global__ void prep_btl(const float* __restrict__ tl, _Float16* __restrict__ Btl) {
  const int idx = blockIdx.x * 256 + threadIdx.x;
  const int p = idx % 224;
  const int n = idx / 224;
  float v = 0.f;
  if (n < 32 && p < 196) v = tl[n * 196 + p];
  Btl[idx] = (_Float16)v;
}

__global__ void zero_pads(_Float16* __restrict__ Mt2, _Float16* __restrict__ MtF,
                          _Float16* __restrict__ MtL) {
  const int idx = blockIdx.x * 256 + threadIdx.x;
  if (idx < 196608) {
    _Float16* p = Mt2 + (size_t)idx * LDA2 + 196;
#pragma unroll
    for (int j = 0; j < 36; j++) p[j] = (_Float16)0.f;
  }
  if (idx < 4096) {
    _Float16* p = MtF + (size_t)idx * KP + 196;
    _Float16* q = MtL + (size_t)idx * KP + 196;
#pragma unroll
    for (int j = 0; j < 28; j++) { p[j] = (_Float16)0.f; q[j] = (_Float16)0.f; }
  }
}

extern "C" void kernel_launch(void* const* d_in, const int* in_sizes, int n_in,
                              void* d_out, int out_size, void* d_ws, size_t ws_size,
                              hipStream_t stream)
{
  const float* x  = (const float*)d_in[0];
  const float* cf = (const float*)d_in[1];
  const float* cm = (const float*)d_in[2];
  const float* cl = (const float*)d_in[3];
  const float* tf = (const float*)d_in[4];
  const float* tm = (const float*)d_in[5];
  const float* tl = (const float*)d_in[6];
  float* out = (float*)d_out;

  char* w = (char*)d_ws;
  auto alloc = [&](size_t bytes) { char* p = w; w += (bytes + 255) & ~(size_t)255; return p; };
  _Float16* xh  = (_Float16*)alloc(100352ull * 64 * 2);
  _Float16* Ckt = (_Float16*)alloc(512ull * 64 * 2);
  _Float16* Mt2 = (_Float16*)alloc(512ull * 384 * LDA2 * 2);
  _Float16* MtF = (_Float16*)alloc(8ull * 512 * KP * 2);
  _Float16* MtL = (_Float16*)alloc(8ull * 512 * KP * 2);
  _Float16* Akr = (_Float16*)alloc(6ull * 1024 * KP * 2);
  _Float16* Bt0 = (_Float16*)alloc(384ull * KP * 2);
  _Float16* Btl = (_Float16*)alloc(128ull * KP * 2);
  float* stA    = (float*)alloc(512ull * 2560 * 4);
  float* GN     = (float*)alloc(4096ull * 32 * 4);
  (void)ws_size; (void)in_sizes; (void)n_in; (void)out_size;

  prep_xh <<<25088, 256, 0, stream>>>(x, xh);
  prep_ckt<<<  128, 256, 0, stream>>>(cf, cm, cl, Ckt);
  prep_akr<<< 5376, 256, 0, stream>>>(tm, Akr);
  prep_bt0<<<  336, 256, 0, stream>>>(tf, Bt0);
  prep_btl<<<  112, 256, 0, stream>>>(tl, Btl);
  zero_pads<<<  768, 256, 0, stream>>>(Mt2, MtF, MtL);

  gemm_mfma<QP, 0><<<dim3(784, 4), 256, 0, stream>>>(Ckt, xh, Mt2, MtF, MtL);
  gemm_mfma<KP, 2><<<dim3(3, 32), 256, 0, stream>>>(MtF, Bt0, stA, nullptr, nullptr);
  gemm_mfma<KP, 3><<<dim3(1, 32), 256, 0, stream>>>(MtL, Btl, GN, nullptr, nullptr);

  chain_kernel<<<512, 512, 0, stream>>>(Mt2, Akr, stA, GN, out);
}

// Round 4
// 334.148 us; speedup vs baseline: 1.0561x; 1.0561x over previous
//
#include <hip/hip_runtime.h>

// TensorConvolutionTrainLayer: S=512,P=196,Q=48,CB=8,R=32,C=10,N=8
// R8: R7 (8 waves/block) regressed 1.5x -> more waves in the SAME block worsen
// the barrier convoy. R5 proved LDS traffic is not the limit (8x cut, 0 delta)
// and that the compiler keeps a whole 64x224 A-tile in AGPRs across a k-step.
// Structure change: (a) drop Ash; af[7][4] loaded straight from a fragment-
// ordered Mt2F (28 coalesced 16B/lane global loads per wave per k, AGPR-
// resident); (b) freed LDS buys SUPER-CHUNKS: Gsh buffers hold 2 cc-chunks
// (64 k' cols, stride 70 halfs -> gcd(35,32)=1 bank rotation), ONE barrier per
// 2 chunks (24+6 barriers/kernel vs 49), 112-MFMA uninterrupted G trains.
//   Per super-chunk sc (cc=2sc,2sc+1): G even -> pack/write col 0..31 ->
//   G odd -> pack/write col 32..63 -> barrier -> NS over both k'-windows.
//   St3[c][l*8+sigma(a)] f16 doubles as state storage AND next B-operand.
//   sigma(a)=(a&1)*4+(a>>1): lane's 4 mi-values k'-contiguous (b64 packs).

typedef _Float16 half8 __attribute__((ext_vector_type(8)));
typedef _Float16 half4 __attribute__((ext_vector_type(4)));
typedef float floatx4 __attribute__((ext_vector_type(4)));

#define KP 224     // P padded to 7*32
#define QP 64      // Q padded to 2*32
#define GSTR2 70   // Gsh row stride (halfs) = 35 dwords, gcd(35,32)=1 -> rotation
#define SSTR 264   // St3 row stride (halfs): 528B, 16B-aligned

__device__ __forceinline__ void gld_lds16(const void* g, void* l) {
  __builtin_amdgcn_global_load_lds((const __attribute__((address_space(1))) void*)g,
                                   (__attribute__((address_space(3))) void*)l, 16, 0, 0);
}

// ---------------- generic MFMA GEMM ----------------
// MODE 0 now writes Mt2 in FRAGMENT layout Mt2F:
//   elem (s, kblk, ab-row, p) -> [(((s*6+kblk)*7 + kt)*4 + mi)*64 + fq*16+fr]*8 + el
//   with kt=p>>5, fq=(p&31)>>3, el=p&7, mi=ab>>4, fr=ab&15.
template<int K, int MODE>
__global__ __launch_bounds__(256)
void gemm_mfma(const _Float16* __restrict__ A, const _Float16* __restrict__ Bt,
               void* __restrict__ out0, void* __restrict__ out1, void* __restrict__ out2)
{
  __shared__ __align__(16) _Float16 Ash[128 * 32];
  __shared__ __align__(16) _Float16 Bsh[128 * 32];
  const int tid  = threadIdx.x;
  const int wave = tid >> 6;
  const int lane = tid & 63;
  const int m0 = blockIdx.y * 128;
  const int n0 = blockIdx.x * 128;
  const int wm = (wave >> 1) * 64;
  const int wn = (wave & 1) * 64;
  const int fr = lane & 15;
  const int fq = lane >> 4;

  floatx4 acc[4][4] = {};

  for (int kt = 0; kt < K; kt += 32) {
    __syncthreads();
#pragma unroll
    for (int j = 0; j < 2; j++) {
      const int c   = j * 256 + tid;
      const int row = c >> 2;
      const int ko  = (c & 3) * 8;
      gld_lds16(A  + (size_t)(m0 + row) * K + kt + ko,
                (char*)Ash + (size_t)(j * 256 + wave * 64) * 16);
      gld_lds16(Bt + (size_t)(n0 + row) * K + kt + ko,
                (char*)Bsh + (size_t)(j * 256 + wave * 64) * 16);
    }
    __syncthreads();
    half8 af[4], bf[4];
#pragma unroll
    for (int i = 0; i < 4; i++)
      af[i] = *(const half8*)&Ash[(wm + i * 16 + fr) * 32 + fq * 8];
#pragma unroll
    for (int i = 0; i < 4; i++)
      bf[i] = *(const half8*)&Bsh[(wn + i * 16 + fr) * 32 + fq * 8];
#pragma unroll
    for (int i = 0; i < 4; i++)
#pragma unroll
      for (int j = 0; j < 4; j++)
        acc[i][j] = __builtin_amdgcn_mfma_f32_16x16x32_f16(af[i], bf[j], acc[i][j], 0, 0, 0);
  }

#pragma unroll
  for (int i = 0; i < 4; i++) {
#pragma unroll
    for (int j = 0; j < 4; j++) {
#pragma unroll
      for (int r = 0; r < 4; r++) {
        const int m = m0 + wm + i * 16 + fq * 4 + r;
        const int n = n0 + wn + j * 16 + fr;
        const float v = acc[i][j][r];
        if constexpr (MODE == 0) {
          const unsigned s = (unsigned)n / 196u;
          const unsigned p = (unsigned)n - s * 196u;
          if (m < 8)
            ((_Float16*)out1)[((size_t)m * 512 + s) * KP + p] = (_Float16)v;
          else if (m < 392) {
            const int r0 = m - 8;
            const int kblk = r0 >> 6, ab = r0 & 63;
            const int mi = ab >> 4, frr = ab & 15;
            const int kt2 = (int)p >> 5, pw = (int)p & 31;
            const int fq2 = pw >> 3, el = pw & 7;
            ((_Float16*)out0)[((((size_t)s * 6 + kblk) * 7 + kt2) * 4 + mi) * 512
                              + (fq2 * 16 + frr) * 8 + el] = (_Float16)v;
          } else if (m < 400)
            ((_Float16*)out2)[((size_t)(m - 392) * 512 + s) * KP + p] = (_Float16)v;
        } else if constexpr (MODE == 2) {
          if (n < 320)
            ((float*)out0)[(size_t)(m & 511) * 2560 + (m >> 9) * 320 + n] = v;
        } else {
          if (n < 32)
            ((float*)out0)[(size_t)m * 32 + n] = v;
        }
      }
    }
  }
}

// ---------------- fused chain kernel (4 waves, super-chunks) ----------------
__global__ __launch_bounds__(256, 2)
void chain_kernel(const _Float16* __restrict__ Mt2F, const _Float16* __restrict__ Akr,
                  const float* __restrict__ St0, const float* __restrict__ GN,
                  float* __restrict__ out)
{
  __shared__ __align__(16) _Float16 Gsh[2][256 * GSTR2];   // 71680 B
  __shared__ __align__(16) _Float16 St3[16 * SSTR];        // 8448 B
  __shared__ float oc[10];

  const int tid  = threadIdx.x;
  const int wave = tid >> 6;
  const int lane = tid & 63;
  const int s    = blockIdx.x;
  const int fr   = lane & 15;
  const int fq   = lane >> 4;
  const int fqh  = fq >> 1;
  const int fql  = fq & 1;

  // init: St3[c][r*8+sigma(b)] from St0[s][b*320+r*10+c]; tid=(b,r)
  {
    const int b = tid >> 5, r = tid & 31;
    const int kcol = r * 8 + ((b & 1) * 4 + (b >> 1));
    const float* src = St0 + (size_t)s * 2560 + (size_t)tid * 10;
#pragma unroll
    for (int c = 0; c < 10; c++) St3[c * SSTR + kcol] = (_Float16)src[c];
    if (tid < 10) oc[tid] = 0.f;
  }

  const int boff0 = fr * KP + fq * 8;   // B row offset for ni=0
  const int boff1 = boff0 + 16 * KP;    // ni=1

  // preload rolling B for (k=0, cc=0, kt=0,1)
  half8 bq[2][2];
  {
    const _Float16* Bb = Akr + (size_t)(wave * 32) * KP;
#pragma unroll
    for (int t2 = 0; t2 < 2; t2++) {
      bq[t2][0] = *(const half8*)(Bb + boff0 + t2 * 32);
      bq[t2][1] = *(const half8*)(Bb + boff1 + t2 * 32);
    }
  }
  __syncthreads();   // St3 ready

  for (int k = 0; k < 6; k++) {
    // whole 64x224 A-tile global->reg (fragment-ordered, 16B/lane coalesced);
    // reused across all 8 chunks; R5 proved the compiler keeps this in AGPRs.
    half8 af[7][4];
    {
      const _Float16* Ab = Mt2F + (size_t)(s * 6 + k) * (7 * 4 * 512);
#pragma unroll
      for (int kt = 0; kt < 7; kt++)
#pragma unroll
        for (int mi = 0; mi < 4; mi++)
          af[kt][mi] = *(const half8*)(Ab + ((size_t)kt * 4 + mi) * 512 + lane * 8);
    }

    floatx4 ns[4] = {};   // NS accumulators: 4 m-tiles per wave

#pragma unroll 1
    for (int sc = 0; sc < 4; sc++) {
      _Float16* gb = &Gsh[sc & 1][0];
      const int cc0 = sc * 2;
      const _Float16* Bc0 = Akr + ((size_t)k * 1024 + cc0 * 128 + wave * 32) * KP;
      const _Float16* Bc1 = Bc0 + (size_t)128 * KP;

      // ---- G even chunk: 64 ab x 32 lr (l = 4*cc0 + wave), K=224 ----
      floatx4 accE[4][2] = {};
#pragma unroll
      for (int kt = 0; kt < 7; kt++) {
#pragma unroll
        for (int mi = 0; mi < 4; mi++) {
          accE[mi][0] = __builtin_amdgcn_mfma_f32_16x16x32_f16(af[kt][mi], bq[kt & 1][0], accE[mi][0], 0, 0, 0);
          accE[mi][1] = __builtin_amdgcn_mfma_f32_16x16x32_f16(af[kt][mi], bq[kt & 1][1], accE[mi][1], 0, 0, 0);
        }
        if (kt < 5) {   // rolling prefetch, distance 2 kt
          bq[kt & 1][0] = *(const half8*)(Bc0 + boff0 + (kt + 2) * 32);
          bq[kt & 1][1] = *(const half8*)(Bc0 + boff1 + (kt + 2) * 32);
        }
      }
      // preload odd chunk kt=0,1 (pack below gives ~150cy of latency cover)
#pragma unroll
      for (int t2 = 0; t2 < 2; t2++) {
        bq[t2][0] = *(const half8*)(Bc1 + boff0 + t2 * 32);
        bq[t2][1] = *(const half8*)(Bc1 + boff1 + t2 * 32);
      }
      // pack + write even: k' = 0..31: col = wave*8 + fqh*4 + mi
      {
        const int kcolw = wave * 8 + fqh * 4;
#pragma unroll
        for (int ni = 0; ni < 2; ni++)
#pragma unroll
          for (int rg = 0; rg < 4; rg++) {
            half4 g4;
#pragma unroll
            for (int mi = 0; mi < 4; mi++) g4[mi] = (_Float16)accE[mi][ni][rg];
            const int m = (fql * 4 + rg) * 32 + ni * 16 + fr;
            *(half4*)&gb[m * GSTR2 + kcolw] = g4;
          }
      }

      // ---- G odd chunk ----
      floatx4 accO[4][2] = {};
#pragma unroll
      for (int kt = 0; kt < 7; kt++) {
#pragma unroll
        for (int mi = 0; mi < 4; mi++) {
          accO[mi][0] = __builtin_amdgcn_mfma_f32_16x16x32_f16(af[kt][mi], bq[kt & 1][0], accO[mi][0], 0, 0, 0);
          accO[mi][1] = __builtin_amdgcn_mfma_f32_16x16x32_f16(af[kt][mi], bq[kt & 1][1], accO[mi][1], 0, 0, 0);
        }
        if (kt < 5) {
          bq[kt & 1][0] = *(const half8*)(Bc1 + boff0 + (kt + 2) * 32);
          bq[kt & 1][1] = *(const half8*)(Bc1 + boff1 + (kt + 2) * 32);
        }
      }
      // pack + write odd: k' = 32..63
      {
        const int kcolw = 32 + wave * 8 + fqh * 4;
#pragma unroll
        for (int ni = 0; ni < 2; ni++)
#pragma unroll
          for (int rg = 0; rg < 4; rg++) {
            half4 g4;
#pragma unroll
            for (int mi = 0; mi < 4; mi++) g4[mi] = (_Float16)accO[mi][ni][rg];
            const int m = (fql * 4 + rg) * 32 + ni * 16 + fr;
            *(half4*)&gb[m * GSTR2 + kcolw] = g4;
          }
      }

      __syncthreads();   // both chunks of Gsh[sc&1] visible to all waves

      // refill bq for next super's even chunk AFTER the barrier (the vmcnt(0)
      // drain before s_barrier must not serialize on these loads)
      {
        int nsc = sc + 1, nk = k;
        if (nsc == 4) { nsc = 0; nk = k + 1; }
        if (nk < 6) {
          const _Float16* Bn = Akr + ((size_t)nk * 1024 + nsc * 2 * 128 + wave * 32) * KP;
#pragma unroll
          for (int t2 = 0; t2 < 2; t2++) {
            bq[t2][0] = *(const half8*)(Bn + boff0 + t2 * 32);
            bq[t2][1] = *(const half8*)(Bn + boff1 + t2 * 32);
          }
        }
      }

      // ---- NS: both k'-windows of this super-chunk ----
#pragma unroll
      for (int w2 = 0; w2 < 2; w2++) {
        const half8 bs = *(const half8*)&St3[fr * SSTR + (cc0 + w2) * 32 + fq * 8];
#pragma unroll
        for (int t = 0; t < 4; t++) {
          const half8 aa = *(const half8*)&gb[((wave * 4 + t) * 16 + fr) * GSTR2 + w2 * 32 + fq * 8];
          ns[t] = __builtin_amdgcn_mfma_f32_16x16x32_f16(aa, bs, ns[t], 0, 0, 0);
        }
      }
      // next super's barrier orders these NS reads before Gsh[sc&1] overwrite
    }

    __syncthreads();   // all NS reads of St3 done before overwrite
    // epilogue: NS -> St3 (next step's state / B operand). m=(b,r): k_next = r*8+sigma(b)
    if (fr < 10) {
#pragma unroll
      for (int t = 0; t < 4; t++) {
#pragma unroll
        for (int rg = 0; rg < 4; rg++) {
          const int m = (wave * 4 + t) * 16 + fq * 4 + rg;
          const int b = m >> 5, r = m & 31;
          St3[fr * SSTR + r * 8 + ((b & 1) * 4 + (b >> 1))] = (_Float16)ns[t][rg];
        }
      }
    }
    // next k's first super barrier orders these writes before any NS read
  }
  __syncthreads();

  // final: out[s,c] = sum_{a,l} St3[c][l*8+sigma(a)] * GN[a][s][l]
  {
    const int a = tid >> 5, l = tid & 31;
    const float gn = GN[((size_t)a * 512 + s) * 32 + l];
    const int kcol = l * 8 + ((a & 1) * 4 + (a >> 1));
#pragma unroll
    for (int c = 0; c < 10; c++) {
      float v = gn * (float)St3[c * SSTR + kcol];
#pragma unroll
      for (int o2 = 1; o2 < 64; o2 <<= 1) v += __shfl_xor(v, o2, 64);
      if (lane == 0) atomicAdd(&oc[c], v);
    }
    __syncthreads();
    if (tid < 10) out[(size_t)s * 10 + tid] = oc[tid];
  }
}

// ---------------- prep kernels ----------------
__global__ void prep_xh(const float* __restrict__ x, _Float16* __restrict__ xh) {
  const int idx = blockIdx.x * 256 + threadIdx.x;
  const int q = idx & 63, sp = idx >> 6;
  xh[idx] = (q < 48) ? (_Float16)x[sp * 48 + q] : (_Float16)0.f;
}

__global__ void prep_ckt(const float* __restrict__ cf, const float* __restrict__ cm,
                         const float* __restrict__ cl, _Float16* __restrict__ Ckt) {
  const int idx = blockIdx.x * 256 + threadIdx.x;
  const int q = idx & 63;
  const int row = idx >> 6;
  float v = 0.f;
  if (q < 48) {
    if (row < 8) v = cf[q * 8 + row];
    else if (row < 392) {
      const int rr = row - 8;
      const int k = rr >> 6, ab = rr & 63, a = ab >> 3, b = ab & 7;
      v = cm[((k * 8 + a) * 48 + q) * 8 + b];
    } else if (row < 400) v = cl[(row - 392) * 48 + q];
  }
  Ckt[idx] = (_Float16)v;
}

__global__ void prep_akr(const float* __restrict__ tm, _Float16* __restrict__ Akr) {
  const int idx = blockIdx.x * 256 + threadIdx.x;
  const int p = idx % 224;
  const int lr = (idx / 224) & 1023;
  const int k = idx / (224 * 1024);
  const int l = lr >> 5, r = lr & 31;
  float v = 0.f;
  if (p < 196) v = tm[(((k * 32 + l) * 196) + p) * 32 + r];
  Akr[idx] = (_Float16)v;
}

__global__ void prep_bt0(const float* __restrict__ tf, _Float16* __restrict__ Bt0) {
  const int idx = blockIdx.x * 256 + threadIdx.x;
  const int p = idx % 224;
  const int n = idx / 224;
  float v = 0.f;
  if (n < 320 && p < 196) {
    const int r = n / 10, c = n % 10;
    v = tf[(c * 196 + p) * 32 + r];
  }
  Bt0[idx] = (_Float16)v;
}

__global__ void prep_btl(const float* __restrict__ tl, _Float16* __restrict__ Btl) {
  const int idx = blockIdx.x * 256 + threadIdx.x;
  const int p = idx % 224;
  const int n = idx / 224;
  float v = 0.f;
  if (n < 32 && p < 196) v = tl[n * 196 + p];
  Btl[idx] = (_Float16)v;
}

// zero the p=196..223 pad in Mt2F fragment layout (kt=6, fq*8+el >= 4) + MtF/MtL pads
__global__ void zero_pads(_Float16* __restrict__ Mt2F, _Float16* __restrict__ MtF,
                          _Float16* __restrict__ MtL) {
  const int idx = blockIdx.x * 256 + threadIdx.x;
  if (idx < 196608) {
    const int s = idx / 384, r0 = idx - s * 384;
    const int kblk = r0 >> 6, ab = r0 & 63;
    const int mi = ab >> 4, fr = ab & 15;
    _Float16* base = Mt2F + ((((size_t)s * 6 + kblk) * 7 + 6) * 4 + mi) * 512 + fr * 8;
#pragma unroll
    for (int el = 4; el < 8; el++) base[el] = (_Float16)0.f;
#pragma unroll
    for (int fq = 1; fq < 4; fq++)
#pragma unroll
      for (int el = 0; el < 8; el++) base[fq * 128 + el] = (_Float16)0.f;
  }
  if (idx < 4096) {
    _Float16* p = MtF + (size_t)idx * KP + 196;
    _Float16* q = MtL + (size_t)idx * KP + 196;
#pragma unroll
    for (int j = 0; j < 28; j++) { p[j] = (_Float16)0.f; q[j] = (_Float16)0.f; }
  }
}

extern "C" void kernel_launch(void* const* d_in, const int* in_sizes, int n_in,
                              void* d_out, int out_size, void* d_ws, size_t ws_size,
                              hipStream_t stream)
{
  const float* x  = (const float*)d_in[0];
  const float* cf = (const float*)d_in[1];
  const float* cm = (const float*)d_in[2];
  const float* cl = (const float*)d_in[3];
  const float* tf = (const float*)d_in[4];
  const float* tm = (const float*)d_in[5];
  const float* tl = (const float*)d_in[6];
  float* out = (float*)d_out;

  char* w = (char*)d_ws;
  auto alloc = [&](size_t bytes) { char* p = w; w += (bytes + 255) & ~(size_t)255; return p; };
  _Float16* xh   = (_Float16*)alloc(100352ull * 64 * 2);
  _Float16* Ckt  = (_Float16*)alloc(512ull * 64 * 2);
  _Float16* Mt2F = (_Float16*)alloc(512ull * 6 * 7 * 4 * 512 * 2);   // 88 MB fragment layout
  _Float16* MtF  = (_Float16*)alloc(8ull * 512 * KP * 2);
  _Float16* MtL  = (_Float16*)alloc(8ull * 512 * KP * 2);
  _Float16* Akr  = (_Float16*)alloc(6ull * 1024 * KP * 2);
  _Float16* Bt0  = (_Float16*)alloc(384ull * KP * 2);
  _Float16* Btl  = (_Float16*)alloc(128ull * KP * 2);
  float* stA     = (float*)alloc(512ull * 2560 * 4);
  float* GN      = (float*)alloc(4096ull * 32 * 4);
  (void)ws_size; (void)in_sizes; (void)n_in; (void)out_size;

  prep_xh <<<25088, 256, 0, stream>>>(x, xh);
  prep_ckt<<<  128, 256, 0, stream>>>(cf, cm, cl, Ckt);
  prep_akr<<< 5376, 256, 0, stream>>>(tm, Akr);
  prep_bt0<<<  336, 256, 0, stream>>>(tf, Bt0);
  prep_btl<<<  112, 256, 0, stream>>>(tl, Btl);
  zero_pads<<<  768, 256, 0, stream>>>(Mt2F, MtF, MtL);

  gemm_mfma<QP, 0><<<dim3(784, 4), 256, 0, stream>>>(Ckt, xh, Mt2F, MtF, MtL);
  gemm_mfma<KP, 2><<<dim3(3, 32), 256, 0, stream>>>(MtF, Bt0, stA, nullptr, nullptr);
  gemm_mfma<KP, 3><<<dim3(1, 32), 256, 0, stream>>>(MtL, Btl, GN, nullptr, nullptr);

  chain_kernel<<<512, 256, 0, stream>>>(Mt2F, Akr, stA, GN, out);
}

// Round 5
// 268.616 us; speedup vs baseline: 1.3137x; 1.2440x over previous
//
#include <hip/hip_runtime.h>

// TensorConvolutionTrainLayer: S=512,P=196,Q=48,CB=8,R=32,C=10,N=8
// R9: barrier-free chunk pipeline. R8's confound resolved: keep Ash (staged
// once/k via global_load_lds; af hoisted to regs/AGPRs from LDS per R5), keep
// 4 waves; the change is WAVE OWNERSHIP: each wave's G slice is B-cols
// (4 l) x (its own 8 r), so G output rows m=(b,r) for NS are produced by the
// SAME wave. The (ab,lr)->(m,k') transpose becomes intra-wave through a
// PRIVATE 64x40 Gsh region: no per-chunk barriers (49 -> 13), no double
// buffer (program-order LDS deps), waves run 48-chunk pipelines independently.
//   a=mi*2+fqh, b=fql*4+rg, l=ni*2+(fr>>3), rr=fr&7
//   Gsh[m=b*8+rr][k'=l*8+sigma(a)], sigma(a)=fqh*4+mi -> mi contiguous (b64)
//   NS: ns[t] += mfma(Gsh rows t*16+fr, St3 rows c, K=32 window cc)
//   epilogue: St3[c][(wave*8+rr)*8+sigma(b)] <- ns (wave-disjoint columns)
// B prefetch: full-chunk distance bf[7][2], rolled per-kt (R4's proven cover).

typedef _Float16 half8 __attribute__((ext_vector_type(8)));
typedef _Float16 half4 __attribute__((ext_vector_type(4)));
typedef float floatx4 __attribute__((ext_vector_type(4)));

#define KP 224    // P padded to 7*32
#define QP 64     // Q padded to 2*32
#define LDA2 232  // Mt2/Ash row stride (halfs) = 29 x 16B chunks
#define GSTR 40   // Gsh row stride (halfs): 80B rows -> b128-aligned
#define SSTR 264  // St3 row stride (halfs): 528B, 16B-aligned

__device__ __forceinline__ void gld_lds16(const void* g, void* l) {
  __builtin_amdgcn_global_load_lds((const __attribute__((address_space(1))) void*)g,
                                   (__attribute__((address_space(3))) void*)l, 16, 0, 0);
}

// ---------------- generic MFMA GEMM (unchanged from R4/R5) ----------------
template<int K, int MODE>
__global__ __launch_bounds__(256)
void gemm_mfma(const _Float16* __restrict__ A, const _Float16* __restrict__ Bt,
               void* __restrict__ out0, void* __restrict__ out1, void* __restrict__ out2)
{
  __shared__ __align__(16) _Float16 Ash[128 * 32];
  __shared__ __align__(16) _Float16 Bsh[128 * 32];
  const int tid  = threadIdx.x;
  const int wave = tid >> 6;
  const int lane = tid & 63;
  const int m0 = blockIdx.y * 128;
  const int n0 = blockIdx.x * 128;
  const int wm = (wave >> 1) * 64;
  const int wn = (wave & 1) * 64;
  const int fr = lane & 15;
  const int fq = lane >> 4;

  floatx4 acc[4][4] = {};

  for (int kt = 0; kt < K; kt += 32) {
    __syncthreads();
#pragma unroll
    for (int j = 0; j < 2; j++) {
      const int c   = j * 256 + tid;
      const int row = c >> 2;
      const int ko  = (c & 3) * 8;
      gld_lds16(A  + (size_t)(m0 + row) * K + kt + ko,
                (char*)Ash + (size_t)(j * 256 + wave * 64) * 16);
      gld_lds16(Bt + (size_t)(n0 + row) * K + kt + ko,
                (char*)Bsh + (size_t)(j * 256 + wave * 64) * 16);
    }
    __syncthreads();
    half8 af[4], bf[4];
#pragma unroll
    for (int i = 0; i < 4; i++)
      af[i] = *(const half8*)&Ash[(wm + i * 16 + fr) * 32 + fq * 8];
#pragma unroll
    for (int i = 0; i < 4; i++)
      bf[i] = *(const half8*)&Bsh[(wn + i * 16 + fr) * 32 + fq * 8];
#pragma unroll
    for (int i = 0; i < 4; i++)
#pragma unroll
      for (int j = 0; j < 4; j++)
        acc[i][j] = __builtin_amdgcn_mfma_f32_16x16x32_f16(af[i], bf[j], acc[i][j], 0, 0, 0);
  }

#pragma unroll
  for (int i = 0; i < 4; i++) {
#pragma unroll
    for (int j = 0; j < 4; j++) {
#pragma unroll
      for (int r = 0; r < 4; r++) {
        const int m = m0 + wm + i * 16 + fq * 4 + r;
        const int n = n0 + wn + j * 16 + fr;
        const float v = acc[i][j][r];
        if constexpr (MODE == 0) {
          const unsigned s = (unsigned)n / 196u;
          const unsigned p = (unsigned)n - s * 196u;
          if (m < 8)
            ((_Float16*)out1)[((size_t)m * 512 + s) * KP + p] = (_Float16)v;
          else if (m < 392)
            ((_Float16*)out0)[((size_t)s * 384 + (m - 8)) * LDA2 + p] = (_Float16)v;
          else if (m < 400)
            ((_Float16*)out2)[((size_t)(m - 392) * 512 + s) * KP + p] = (_Float16)v;
        } else if constexpr (MODE == 2) {
          if (n < 320)
            ((float*)out0)[(size_t)(m & 511) * 2560 + (m >> 9) * 320 + n] = v;
        } else {
          if (n < 32)
            ((float*)out0)[(size_t)m * 32 + n] = v;
        }
      }
    }
  }
}

// ---------------- fused chain kernel (4 waves, barrier-free chunks) ----------------
__device__ __forceinline__ void stageA(const _Float16* __restrict__ base,
                                       _Float16* __restrict__ ash, int tid) {
  const int wave = tid >> 6;
#pragma unroll
  for (int it = 0; it < 7; it++) {
    const int c = it * 256 + tid;
    gld_lds16(base + (size_t)c * 8, (char*)ash + (size_t)(it * 256 + wave * 64) * 16);
  }
  if (tid < 64)
    gld_lds16(base + (size_t)(1792 + tid) * 8, (char*)ash + (size_t)1792 * 16);
}

__global__ __launch_bounds__(256, 2)
void chain_kernel(const _Float16* __restrict__ Mt2, const _Float16* __restrict__ Akr,
                  const float* __restrict__ St0, const float* __restrict__ GN,
                  float* __restrict__ out)
{
  __shared__ __align__(16) _Float16 Ash[64 * LDA2];        // 29696 B
  __shared__ __align__(16) _Float16 Gsh[4][64 * GSTR];     // 20480 B (per-wave private)
  __shared__ __align__(16) _Float16 St3[16 * SSTR];        // 8448 B
  __shared__ float oc[10];

  const int tid  = threadIdx.x;
  const int wave = tid >> 6;
  const int lane = tid & 63;
  const int s    = blockIdx.x;
  const int fr   = lane & 15;
  const int fq   = lane >> 4;
  const int fre  = fr & 7;
  const int frh  = fr >> 3;
  const int fqh  = fq >> 1;
  const int fql  = fq & 1;

  // init: St3[c][r*8+sigma(b)] from St0[s][b*320+r*10+c]; tid=(b,r)
  {
    const int b = tid >> 5, r = tid & 31;
    const int kcol = r * 8 + ((b & 1) * 4 + (b >> 1));
    const float* src = St0 + (size_t)s * 2560 + (size_t)tid * 10;
#pragma unroll
    for (int c = 0; c < 10; c++) St3[c * SSTR + kcol] = (_Float16)src[c];
    if (tid < 10) oc[tid] = 0.f;
  }
  stageA(Mt2 + (size_t)s * 384 * LDA2, Ash, tid);

  // B lane offsets: G B-cols n = ni*16+fr -> l = ni*2+frh, rr = fre (wave's r-slice)
  const size_t lb0 = (size_t)((0 * 2 + frh) * 32 + wave * 8 + fre) * KP + fq * 8;
  const size_t lb1 = (size_t)((1 * 2 + frh) * 32 + wave * 8 + fre) * KP + fq * 8;

  // full-chunk-distance B prefetch: bf[kt][ni] for (k=0, cc=0)
  half8 bf[7][2];
#pragma unroll
  for (int kt = 0; kt < 7; kt++) {
    bf[kt][0] = *(const half8*)(Akr + lb0 + kt * 32);
    bf[kt][1] = *(const half8*)(Akr + lb1 + kt * 32);
  }
  __syncthreads();   // Ash + St3 ready (compiler drains vmcnt before barrier)

  _Float16* gw = &Gsh[wave][0];

  for (int k = 0; k < 6; k++) {
    // af hoist: whole 64x224 A-tile -> regs once per k (R5: compiler AGPRs it)
    half8 af[7][4];
#pragma unroll
    for (int kt = 0; kt < 7; kt++)
#pragma unroll
      for (int mi = 0; mi < 4; mi++)
        af[kt][mi] = *(const half8*)&Ash[(mi * 16 + fr) * LDA2 + kt * 32 + fq * 8];
    __syncthreads();   // bar1: all af reads complete -> Ash free for restage
    if (k < 5) stageA(Mt2 + ((size_t)s * 384 + 64 * (k + 1)) * LDA2, Ash, tid);

    floatx4 ns[4] = {};

#pragma unroll 1
    for (int cc = 0; cc < 8; cc++) {
      int ncc = cc + 1, nk = k;
      if (ncc == 8) { ncc = 0; nk = k + 1; }
      const _Float16* Bn = Akr + ((size_t)nk * 1024 + ncc * 128) * KP;
      const bool pf = (nk < 6);

      // ---- G-phase: wave's 64 ab x 32 (4l x own 8r) slice, K=224 ----
      floatx4 acc[4][2] = {};
#pragma unroll
      for (int kt = 0; kt < 7; kt++) {
#pragma unroll
        for (int mi = 0; mi < 4; mi++) {
          acc[mi][0] = __builtin_amdgcn_mfma_f32_16x16x32_f16(af[kt][mi], bf[kt][0], acc[mi][0], 0, 0, 0);
          acc[mi][1] = __builtin_amdgcn_mfma_f32_16x16x32_f16(af[kt][mi], bf[kt][1], acc[mi][1], 0, 0, 0);
        }
        if (pf) {   // roll bf[kt] to next chunk right after last use (~full-chunk cover)
          bf[kt][0] = *(const half8*)(Bn + lb0 + kt * 32);
          bf[kt][1] = *(const half8*)(Bn + lb1 + kt * 32);
        }
      }

      // ---- pack + write to PRIVATE Gsh region (no barrier needed) ----
      // lane value (mi,ni,rg): row m = b*8+rr = (fql*4+rg)*8+fre,
      // col k' = l*8+sigma(a) = (ni*2+frh)*8 + fqh*4 + mi  (mi contiguous)
#pragma unroll
      for (int ni = 0; ni < 2; ni++)
#pragma unroll
        for (int rg = 0; rg < 4; rg++) {
          half4 g4;
#pragma unroll
          for (int mi = 0; mi < 4; mi++) g4[mi] = (_Float16)acc[mi][ni][rg];
          *(half4*)&gw[((fql * 4 + rg) * 8 + fre) * GSTR + (ni * 2 + frh) * 8 + fqh * 4] = g4;
        }

      // ---- NS: own rows, K=32 window cc (same-wave LDS dep, compiler orders) ----
      const half8 bs = *(const half8*)&St3[fr * SSTR + cc * 32 + fq * 8];
#pragma unroll
      for (int t = 0; t < 4; t++) {
        const half8 aa = *(const half8*)&gw[(t * 16 + fr) * GSTR + fq * 8];
        ns[t] = __builtin_amdgcn_mfma_f32_16x16x32_f16(aa, bs, ns[t], 0, 0, 0);
      }
    }

    __syncthreads();   // bar2: all NS reads of St3 done; stage(k+1) drained
    // epilogue: ns -> St3 (wave-disjoint columns). m=t*16+fq*4+rg -> b=m>>3, rr=m&7
    if (fr < 10) {
#pragma unroll
      for (int t = 0; t < 4; t++) {
#pragma unroll
        for (int rg = 0; rg < 4; rg++) {
          const int m = t * 16 + fq * 4 + rg;
          const int b = m >> 3, rr = m & 7;
          St3[fr * SSTR + (wave * 8 + rr) * 8 + (b & 1) * 4 + (b >> 1)] = (_Float16)ns[t][rg];
        }
      }
    }
    // next k's bar1 orders these writes before any NS read of k+1
  }
  __syncthreads();

  // final: out[s,c] = sum_{a,l} St3[c][l*8+sigma(a)] * GN[a][s][l]
  {
    const int a = tid >> 5, l = tid & 31;
    const float gn = GN[((size_t)a * 512 + s) * 32 + l];
    const int kcol = l * 8 + ((a & 1) * 4 + (a >> 1));
#pragma unroll
    for (int c = 0; c < 10; c++) {
      float v = gn * (float)St3[c * SSTR + kcol];
#pragma unroll
      for (int o2 = 1; o2 < 64; o2 <<= 1) v += __shfl_xor(v, o2, 64);
      if (lane == 0) atomicAdd(&oc[c], v);
    }
    __syncthreads();
    if (tid < 10) out[(size_t)s * 10 + tid] = oc[tid];
  }
}

// ---------------- prep kernels (unchanged) ----------------
__global__ void prep_xh(const float* __restrict__ x, _Float16* __restrict__ xh) {
  const int idx = blockIdx.x * 256 + threadIdx.x;
  const int q = idx & 63, sp = idx >> 6;
  xh[idx] = (q < 48) ? (_Float16)x[sp * 48 + q] : (_Float16)0.f;
}

__global__ void prep_ckt(const float* __restrict__ cf, const float* __restrict__ cm,
                         const float* __restrict__ cl, _Float16* __restrict__ Ckt) {
  const int idx = blockIdx.x * 256 + threadIdx.x;
  const int q = idx & 63;
  const int row = idx >> 6;
  float v = 0.f;
  if (q < 48) {
    if (row < 8) v = cf[q * 8 + row];
    else if (row < 392) {
      const int rr = row - 8;
      const int k = rr >> 6, ab = rr & 63, a = ab >> 3, b = ab & 7;
      v = cm[((k * 8 + a) * 48 + q) * 8 + b];
    } else if (row < 400) v = cl[(row - 392) * 48 + q];
  }
  Ckt[idx] = (_Float16)v;
}

__global__ void prep_akr(const float* __restrict__ tm, _Float16* __restrict__ Akr) {
  const int idx = blockIdx.x * 256 + threadIdx.x;
  const int p = idx % 224;
  const int lr = (idx / 224) & 1023;
  const int k = idx / (224 * 1024);
  const int l = lr >> 5, r = lr & 31;
  float v = 0.f;
  if (p < 196) v = tm[(((k * 32 + l) * 196) + p) * 32 + r];
  Akr[idx] = (_Float16)v;
}

__global__ void prep_bt0(const float* __restrict__ tf, _Float16* __restrict__ Bt0) {
  const int idx = blockIdx.x * 256 + threadIdx.x;
  const int p = idx % 224;
  const int n = idx / 224;
  float v = 0.f;
  if (n < 320 && p < 196) {
    const int r = n / 10, c = n % 10;
    v = tf[(c * 196 + p) * 32 + r];
  }
  Bt0[idx] = (_Float16)v;
}

__global__ void prep_btl(const float* __restrict__ tl, _Float16* __restrict__ Btl) {
  const int idx = blockIdx.x * 256 + threadIdx.x;
  const int p = idx % 224;
  const int n = idx / 224;
  float v = 0.f;
  if (n < 32 && p < 196) v = tl[n * 196 + p];
  Btl[idx] = (_Float16)v;
}

__global__ void zero_pads(_Float16* __restrict__ Mt2, _Float16* __restrict__ MtF,
                          _Float16* __restrict__ MtL) {
  const int idx = blockIdx.x * 256 + threadIdx.x;
  if (idx < 196608) {
    _Float16* p = Mt2 + (size_t)idx * LDA2 + 196;
#pragma unroll
    for (int j = 0; j < 36; j++) p[j] = (_Float16)0.f;
  }
  if (idx < 4096) {
    _Float16* p = MtF + (size_t)idx * KP + 196;
    _Float16* q = MtL + (size_t)idx * KP + 196;
#pragma unroll
    for (int j = 0; j < 28; j++) { p[j] = (_Float16)0.f; q[j] = (_Float16)0.f; }
  }
}

extern "C" void kernel_launch(void* const* d_in, const int* in_sizes, int n_in,
                              void* d_out, int out_size, void* d_ws, size_t ws_size,
                              hipStream_t stream)
{
  const float* x  = (const float*)d_in[0];
  const float* cf = (const float*)d_in[1];
  const float* cm = (const float*)d_in[2];
  const float* cl = (const float*)d_in[3];
  const float* tf = (const float*)d_in[4];
  const float* tm = (const float*)d_in[5];
  const float* tl = (const float*)d_in[6];
  float* out = (float*)d_out;

  char* w = (char*)d_ws;
  auto alloc = [&](size_t bytes) { char* p = w; w += (bytes + 255) & ~(size_t)255; return p; };
  _Float16* xh  = (_Float16*)alloc(100352ull * 64 * 2);
  _Float16* Ckt = (_Float16*)alloc(512ull * 64 * 2);
  _Float16* Mt2 = (_Float16*)alloc(512ull * 384 * LDA2 * 2);
  _Float16* MtF = (_Float16*)alloc(8ull * 512 * KP * 2);
  _Float16* MtL = (_Float16*)alloc(8ull * 512 * KP * 2);
  _Float16* Akr = (_Float16*)alloc(6ull * 1024 * KP * 2);
  _Float16* Bt0 = (_Float16*)alloc(384ull * KP * 2);
  _Float16* Btl = (_Float16*)alloc(128ull * KP * 2);
  float* stA    = (float*)alloc(512ull * 2560 * 4);
  float* GN     = (float*)alloc(4096ull * 32 * 4);
  (void)ws_size; (void)in_sizes; (void)n_in; (void)out_size;

  prep_xh <<<25088, 256, 0, stream>>>(x, xh);
  prep_ckt<<<  128, 256, 0, stream>>>(cf, cm, cl, Ckt);
  prep_akr<<< 5376, 256, 0, stream>>>(tm, Akr);
  prep_bt0<<<  336, 256, 0, stream>>>(tf, Bt0);
  prep_btl<<<  112, 256, 0, stream>>>(tl, Btl);
  zero_pads<<<  768, 256, 0, stream>>>(Mt2, MtF, MtL);

  gemm_mfma<QP, 0><<<dim3(784, 4), 256, 0, stream>>>(Ckt, xh, Mt2, MtF, MtL);
  gemm_mfma<KP, 2><<<dim3(3, 32), 256, 0, stream>>>(MtF, Bt0, stA, nullptr, nullptr);
  gemm_mfma<KP, 3><<<dim3(1, 32), 256, 0, stream>>>(MtL, Btl, GN, nullptr, nullptr);

  chain_kernel<<<512, 256, 0, stream>>>(Mt2, Akr, stA, GN, out);
}